// Round 3
// baseline (448.824 us; speedup 1.0000x reference)
//
#include <hip/hip_runtime.h>
#include <hip/hip_bf16.h>

typedef __hip_bfloat16 bf16;
typedef __attribute__((ext_vector_type(8))) short bf16x8;
typedef __attribute__((ext_vector_type(4))) float f32x4;

// Problem constants: B=64, n=m=14, E=512, D1=1024, heads=8
constexpr int NB    = 64;
constexpr int EE    = 512;
constexpr int DD1   = 1024;
constexpr int RPOS  = 27 * 27;       // 729
constexpr int ROWS  = NB * 14 * 14;  // 12544

#define RMS_EPS 1e-6f
#define GAMMA_LOG2 (-0.00144344319f)   // log2(0.999)

__device__ __forceinline__ float ldf(const float* p)  { return *p; }
__device__ __forceinline__ float ldf(const bf16* p)   { return __bfloat162float(*p); }
__device__ __forceinline__ void  stf(float* p, float v) { *p = v; }
__device__ __forceinline__ void  stf(bf16* p, float v)  { *p = __float2bfloat16(v); }

__device__ __forceinline__ void gload_lds16(const bf16* g, bf16* l) {
    __builtin_amdgcn_global_load_lds(
        (const __attribute__((address_space(1))) void*)g,
        (__attribute__((address_space(3))) void*)l, 16, 0, 0);
}

// ---------------------------------------------------------------------------
__global__ void k_rpe_pos(const float* __restrict__ w, const float* __restrict__ bias,
                          float* __restrict__ out) {
    int p = blockIdx.x;
    float ii = (float)(p / 27 - 13);
    float jj = (float)(p % 27 - 13);
    for (int c = threadIdx.x; c < 512; c += 256)
        out[p * 512 + c] = ii * w[c] + jj * w[512 + c] + bias[c];
}

// ---------------------------------------------------------------------------
__global__ void k_rmsnorm_relu(const float* __restrict__ in, float* __restrict__ out) {
    int r = blockIdx.x;
    const float* x = in + (size_t)r * 512;
    float v0 = x[threadIdx.x];
    float v1 = x[threadIdx.x + 256];
    float s = v0 * v0 + v1 * v1;
    #pragma unroll
    for (int off = 32; off; off >>= 1) s += __shfl_down(s, off, 64);
    __shared__ float ps[4];
    if ((threadIdx.x & 63) == 0) ps[threadIdx.x >> 6] = s;
    __syncthreads();
    float tot = ps[0] + ps[1] + ps[2] + ps[3];
    float scale = rsqrtf(tot * (1.0f / 512.0f) + RMS_EPS);
    out[(size_t)r * 512 + threadIdx.x]       = fmaxf(v0 * scale, 0.0f);
    out[(size_t)r * 512 + threadIdx.x + 256] = fmaxf(v1 * scale, 0.0f);
}

// ---------------------------------------------------------------------------
// VALU GEMM (RPE chain only). EPI: 0 = none, 2 = Toeplitz decay by row.
template <typename TA, int EPI, typename TO>
__global__ __launch_bounds__(256) void k_gemm(const TA* __restrict__ A,
                                              const float* __restrict__ Bw,
                                              const float* __restrict__ bias,
                                              TO* __restrict__ out,
                                              int Mr, int Nc, int Kd) {
    __shared__ float As[16][64];
    __shared__ float Bs[16][64];
    const int m0 = blockIdx.y * 64;
    const int n0 = blockIdx.x * 64;
    const int tid = threadIdx.x;
    const int tr = tid >> 4;
    const int tc = tid & 15;

    float acc[4][4] = {};

    for (int k0 = 0; k0 < Kd; k0 += 16) {
        #pragma unroll
        for (int l = 0; l < 4; ++l) {
            int idx = tid + l * 256;
            int m = idx >> 4, k = idx & 15;
            int gm = m0 + m;
            float val = (gm < Mr) ? ldf(&A[(size_t)gm * Kd + k0 + k]) : 0.0f;
            As[k][m] = val;
        }
        #pragma unroll
        for (int l = 0; l < 4; ++l) {
            int idx = tid + l * 256;
            int k = idx >> 6, n = idx & 63;
            Bs[k][n] = Bw[(size_t)(k0 + k) * Nc + n0 + n];
        }
        __syncthreads();
        #pragma unroll
        for (int kk = 0; kk < 16; ++kk) {
            float4 a4 = *(const float4*)&As[kk][tr * 4];
            float4 b4 = *(const float4*)&Bs[kk][tc * 4];
            float av[4] = {a4.x, a4.y, a4.z, a4.w};
            float bv[4] = {b4.x, b4.y, b4.z, b4.w};
            #pragma unroll
            for (int r = 0; r < 4; ++r)
                #pragma unroll
                for (int c = 0; c < 4; ++c)
                    acc[r][c] = fmaf(av[r], bv[c], acc[r][c]);
        }
        __syncthreads();
    }

    #pragma unroll
    for (int r = 0; r < 4; ++r) {
        int row = m0 + tr * 4 + r;
        if (row >= Mr) break;
        float decay = 1.0f;
        if (EPI == 2) {
            int i = row / 27, j = row % 27;
            float dist = (float)(abs(i - 13) + abs(j - 13));
            decay = exp2f(dist * GAMMA_LOG2);
        }
        #pragma unroll
        for (int c = 0; c < 4; ++c) {
            int col = n0 + tc * 4 + c;
            float val = acc[r][c] + bias[col];
            if (EPI == 2) val *= decay;
            stf(&out[(size_t)row * Nc + col], val);
        }
    }
}

// ---------------------------------------------------------------------------
// MFMA bf16 GEMM (m97 structure): 128x128 tile, BK=32, 4 waves, 4x4 frags.
template <int EPI, typename TO>
__global__ __launch_bounds__(256) void k_mgemm(const bf16* __restrict__ A, int lda,
                                               const bf16* __restrict__ Bt,
                                               const float* __restrict__ bias,
                                               TO* __restrict__ out, int ldo,
                                               int M, int N, int K) {
    __shared__ bf16 As[128 * 32];
    __shared__ bf16 Bs[128 * 32];
    const int tid = threadIdx.x;
    const int m0 = blockIdx.y * 128;
    const int n0 = blockIdx.x * 128;
    const int lane = tid & 63;
    const int w = tid >> 6;
    const int wr = (w >> 1) * 64;
    const int wc = (w & 1) * 64;
    const int lr = lane & 15;
    const int lk = (lane >> 4) * 8;

    f32x4 acc[4][4] = {};

    for (int k0 = 0; k0 < K; k0 += 32) {
        #pragma unroll
        for (int t = 0; t < 2; ++t) {
            int flat = t * 256 + tid;
            int row = flat >> 2;
            int seg = (flat & 3) * 8;
            gload_lds16(&A[(size_t)(m0 + row) * lda + k0 + seg], &As[flat * 8]);
            gload_lds16(&Bt[(size_t)(n0 + row) * K + k0 + seg], &Bs[flat * 8]);
        }
        __syncthreads();
        bf16x8 af[4], bf[4];
        #pragma unroll
        for (int i = 0; i < 4; ++i) {
            af[i] = *(const bf16x8*)&As[(wr + i * 16 + lr) * 32 + lk];
            bf[i] = *(const bf16x8*)&Bs[(wc + i * 16 + lr) * 32 + lk];
        }
        #pragma unroll
        for (int i = 0; i < 4; ++i)
            #pragma unroll
            for (int j = 0; j < 4; ++j)
                acc[i][j] = __builtin_amdgcn_mfma_f32_16x16x32_bf16(af[i], bf[j], acc[i][j], 0, 0, 0);
        __syncthreads();
    }

    const int crow = (lane >> 4) * 4;
    const int ccol = lane & 15;
    #pragma unroll
    for (int i = 0; i < 4; ++i)
        #pragma unroll
        for (int j = 0; j < 4; ++j) {
            int gc = n0 + wc + j * 16 + ccol;
            float bb = bias[gc];
            #pragma unroll
            for (int r = 0; r < 4; ++r) {
                int gr = m0 + wr + i * 16 + crow + r;
                float val = acc[i][j][r] + bb;
                if (EPI == 1) val = val / (1.0f + expf(-val));
                stf(&out[(size_t)gr * ldo + gc], val);
            }
        }
}

// ---------------------------------------------------------------------------
// fp32 [R][C] -> bf16 [C][R] transpose (weights prep)
__global__ __launch_bounds__(256) void k_transpose(const float* __restrict__ src,
                                                   bf16* __restrict__ dst, int R, int C) {
    __shared__ float t[32][33];
    int bx = blockIdx.x * 32;
    int by = blockIdx.y * 32;
    int tx = threadIdx.x & 31, ty = threadIdx.x >> 5;
    #pragma unroll
    for (int i = 0; i < 4; ++i)
        t[ty + i * 8][tx] = src[(size_t)(by + ty + i * 8) * C + bx + tx];
    __syncthreads();
    #pragma unroll
    for (int i = 0; i < 4; ++i)
        dst[(size_t)(bx + ty + i * 8) * R + by + tx] = __float2bfloat16(t[tx][ty + i * 8]);
}

// ---------------------------------------------------------------------------
__global__ void k_cvt_bf16(const float* __restrict__ src, bf16* __restrict__ dst, int n4) {
    int i = blockIdx.x * blockDim.x + threadIdx.x;
    if (i < n4) {
        float4 v = *(const float4*)&src[i * 4];
        bf16* d = &dst[i * 4];
        d[0] = __float2bfloat16(v.x);
        d[1] = __float2bfloat16(v.y);
        d[2] = __float2bfloat16(v.z);
        d[3] = __float2bfloat16(v.w);
    }
}

__global__ void k_bias_uv(const float* __restrict__ bu, const float* __restrict__ bv,
                          float* __restrict__ dst) {
    int c = blockIdx.x * 256 + threadIdx.x;
    if (c < 2048) dst[c] = (c < 1024) ? bu[c] : bv[c - 1024];
}

// ---------------------------------------------------------------------------
// v channel transpose: Vt[c][b][ij(pad 224)] = v[b*196+ij][c]  (v = uvb col 1024+c)
__global__ __launch_bounds__(256) void k_vt(const bf16* __restrict__ uv,
                                            bf16* __restrict__ Vt) {
    const int c0 = blockIdx.x * 64;   // 16 c-tiles
    const int b  = blockIdx.y;        // 0..63
    const int tid = threadIdx.x;
    __shared__ bf16 t[196][66];
    for (int f = tid; f < 196 * 64; f += 256) {
        int ij = f >> 6, cl = f & 63;
        t[ij][cl] = uv[((size_t)b * 196 + ij) * 2048 + 1024 + c0 + cl];
    }
    __syncthreads();
    const bf16 z = __float2bfloat16(0.0f);
    for (int f = tid; f < 64 * 224; f += 256) {
        int cl = f / 224, ij = f - cl * 224;
        Vt[((size_t)(c0 + cl) * 64 + b) * 224 + ij] = (ij < 196) ? t[ij][cl] : z;
    }
}

// ---------------------------------------------------------------------------
// Per-channel Toeplitz GEMM on MFMA: Yt[c][pq][b] = sum_ij T_c[pq][ij] * Vt[c][b][ij]
// Block = (m-half, channel). T-slice (112 rows x 224 K, stride 232) built in LDS
// from the 729 A_c coefficients; B-frags streamed from L2-resident Vt.
__global__ __launch_bounds__(256) void k_convm(const bf16* __restrict__ Ab,
                                               const bf16* __restrict__ Vt,
                                               bf16* __restrict__ Yt, int cbase) {
    __shared__ __align__(16) bf16 Ts[112 * 232];
    __shared__ bf16 As[736];
    const int mh = blockIdx.x;               // 0 / 1
    const int cl = blockIdx.y;               // 0..511 (local channel)
    const int c = cbase + cl;
    const int tid = threadIdx.x;
    const int mbase = mh * 112;
    const int MT = mh ? 6 : 7;               // 16-row M-tiles in this half

    for (int e = tid; e < 729; e += 256)
        As[e] = Ab[(size_t)e * 1024 + c];
    __syncthreads();

    const bf16 z = __float2bfloat16(0.0f);
    for (int e = tid; e < 112 * 224; e += 256) {
        int r = e / 224;
        int k = e - r * 224;
        int pq = mbase + r;
        bf16 val = z;
        if (pq < 196 && k < 196) {
            int p = pq / 14, q = pq - p * 14;
            int i = k / 14,  j = k - i * 14;
            val = As[(p - i + 13) * 27 + (q - j + 13)];
        }
        Ts[r * 232 + k] = val;
    }
    __syncthreads();

    const int lane = tid & 63;
    const int w = tid >> 6;
    const int lr = lane & 15;
    const int lk = (lane >> 4) * 8;
    const bf16* Vc = Vt + (size_t)c * 64 * 224;

    for (int t = w; t < MT * 4; t += 4) {
        int mi = t >> 2, nj = t & 3;
        f32x4 acc = {};
        #pragma unroll
        for (int ks = 0; ks < 7; ++ks) {
            bf16x8 a = *(const bf16x8*)&Ts[(mi * 16 + lr) * 232 + ks * 32 + lk];
            bf16x8 b = *(const bf16x8*)&Vc[(size_t)(nj * 16 + lr) * 224 + ks * 32 + lk];
            acc = __builtin_amdgcn_mfma_f32_16x16x32_bf16(a, b, acc, 0, 0, 0);
        }
        int pq = mbase + mi * 16 + (lane >> 4) * 4;
        int bb = nj * 16 + (lane & 15);
        #pragma unroll
        for (int r = 0; r < 4; ++r)
            if (pq + r < 196)
                Yt[((size_t)cl * 196 + pq + r) * 64 + bb] = __float2bfloat16(acc[r]);
    }
}

// ---------------------------------------------------------------------------
// Gate + transpose back: uv.v[b*196+pq][c] = u[b*196+pq][c] * Yt[c-cbase][pq][b]
__global__ __launch_bounds__(256) void k_gate(bf16* __restrict__ uv,
                                              const bf16* __restrict__ Yt, int cbase) {
    const int pq = blockIdx.x;       // 0..195
    const int ct = blockIdx.y;       // 0..7 (64-ch tiles within half)
    const int tid = threadIdx.x;
    __shared__ float t[64][65];
    for (int f = tid; f < 64 * 64; f += 256) {
        int cr = f >> 6, bcol = f & 63;
        t[cr][bcol] = __bfloat162float(Yt[((size_t)(ct * 64 + cr) * 196 + pq) * 64 + bcol]);
    }
    __syncthreads();
    for (int f = tid; f < 64 * 64; f += 256) {
        int br = f >> 6, cc = f & 63;
        size_t row = (size_t)br * 196 + pq;
        int cglob = cbase + ct * 64 + cc;
        float uu = __bfloat162float(uv[row * 2048 + cglob]);
        uv[row * 2048 + 1024 + cglob] = __float2bfloat16(t[cc][br] * uu);
    }
}

// ---------------------------------------------------------------------------
extern "C" void kernel_launch(void* const* d_in, const int* in_sizes, int n_in,
                              void* d_out, int out_size, void* d_ws, size_t ws_size,
                              hipStream_t stream) {
    const float* x    = (const float*)d_in[0];
    const float* Wu   = (const float*)d_in[3];
    const float* bu   = (const float*)d_in[4];
    const float* Wv   = (const float*)d_in[5];
    const float* bv   = (const float*)d_in[6];
    const float* Wo   = (const float*)d_in[7];
    const float* bo   = (const float*)d_in[8];
    const float* rpw  = (const float*)d_in[9];
    const float* rpb  = (const float*)d_in[10];
    const float* w1   = (const float*)d_in[11];
    const float* b1   = (const float*)d_in[12];
    const float* w2   = (const float*)d_in[13];
    const float* b2   = (const float*)d_in[14];
    const float* w3   = (const float*)d_in[15];
    const float* b3   = (const float*)d_in[16];
    const float* wOut = (const float*)d_in[17];
    const float* bOut = (const float*)d_in[18];

    char* ws = (char*)d_ws;
    size_t off = 0;
    auto take = [&](size_t bytes) { char* p = ws + off; off += (bytes + 255) & ~size_t(255); return p; };
    float* rA     = (float*)take((size_t)RPOS * 512 * 4);
    float* rB     = (float*)take((size_t)RPOS * 512 * 4);
    float* rn     = (float*)take((size_t)RPOS * 512 * 4);
    bf16*  Ab     = (bf16*)take((size_t)RPOS * 1024 * 2);     // Toeplitz coeffs, bf16
    bf16*  xb     = (bf16*)take((size_t)ROWS * EE * 2);        // 12.85 MB (reused as Yt)
    bf16*  WuvT   = (bf16*)take((size_t)2048 * 512 * 2);
    bf16*  WoT    = (bf16*)take((size_t)512 * 1024 * 2);
    float* biasUv = (float*)take(2048 * 4);
    bf16*  uvb    = (bf16*)take((size_t)ROWS * 2048 * 2);
    bf16*  Vt     = (bf16*)take((size_t)1024 * 64 * 224 * 2);  // 29.4 MB
    bf16*  Yt     = (bf16*)xb;   // alias: xb dead once uv GEMM has run

    // --- RPE MLP ---
    k_rpe_pos<<<RPOS, 256, 0, stream>>>(rpw, rpb, rA);
    k_rmsnorm_relu<<<RPOS, 256, 0, stream>>>(rA, rn);
    k_gemm<float, 0, float><<<dim3(8, 12), 256, 0, stream>>>(rn, w1, b1, rB, RPOS, 512, 512);
    k_rmsnorm_relu<<<RPOS, 256, 0, stream>>>(rB, rn);
    k_gemm<float, 0, float><<<dim3(8, 12), 256, 0, stream>>>(rn, w2, b2, rA, RPOS, 512, 512);
    k_rmsnorm_relu<<<RPOS, 256, 0, stream>>>(rA, rn);
    k_gemm<float, 0, float><<<dim3(8, 12), 256, 0, stream>>>(rn, w3, b3, rB, RPOS, 512, 512);
    k_rmsnorm_relu<<<RPOS, 256, 0, stream>>>(rB, rn);
    k_gemm<float, 2, bf16><<<dim3(16, 12), 256, 0, stream>>>(rn, wOut, bOut, Ab, RPOS, 1024, 512);

    // --- prep ---
    k_cvt_bf16<<<(ROWS * EE / 4 + 255) / 256, 256, 0, stream>>>(x, xb, ROWS * EE / 4);
    k_transpose<<<dim3(32, 16), 256, 0, stream>>>(Wu, WuvT, 512, 1024);
    k_transpose<<<dim3(32, 16), 256, 0, stream>>>(Wv, WuvT + (size_t)1024 * 512, 512, 1024);
    k_transpose<<<dim3(16, 32), 256, 0, stream>>>(Wo, WoT, 1024, 512);
    k_bias_uv<<<8, 256, 0, stream>>>(bu, bv, biasUv);

    // --- uv = silu(x @ [Wu|Wv] + [bu|bv]) ---
    k_mgemm<1, bf16><<<dim3(16, 98), 256, 0, stream>>>(xb, 512, WuvT, biasUv, uvb, 2048,
                                                       ROWS, 2048, 512);

    // --- v -> channel-major Vt ---
    k_vt<<<dim3(16, 64), 256, 0, stream>>>(uvb, Vt);

    // --- Toeplitz conv on MFMA + gating, two 512-channel halves (Yt aliases xb) ---
    for (int h = 0; h < 2; ++h) {
        k_convm<<<dim3(2, 512), 256, 0, stream>>>(Ab, Vt, Yt, h * 512);
        k_gate<<<dim3(196, 8), 256, 0, stream>>>(uvb, Yt, h * 512);
    }

    // --- out = g @ Wo + bo ---
    k_mgemm<0, float><<<dim3(4, 98), 256, 0, stream>>>(uvb + 1024, 2048, WoT, bo,
                                                       (float*)d_out, 512, ROWS, 512, 1024);
}

// Round 4
// 258.300 us; speedup vs baseline: 1.7376x; 1.7376x over previous
//
#include <hip/hip_runtime.h>
#include <hip/hip_bf16.h>

typedef __hip_bfloat16 bf16;
typedef __attribute__((ext_vector_type(8))) short bf16x8;
typedef __attribute__((ext_vector_type(4))) float f32x4;

// Problem constants: B=64, n=m=14, E=512, D1=1024, heads=8
constexpr int NB    = 64;
constexpr int EE    = 512;
constexpr int DD1   = 1024;
constexpr int RPOS  = 27 * 27;       // 729
constexpr int ROWS  = NB * 14 * 14;  // 12544

#define RMS_EPS 1e-6f
#define GAMMA_LOG2 (-0.00144344319f)   // log2(0.999)

__device__ __forceinline__ void  stf(float* p, float v) { *p = v; }
__device__ __forceinline__ void  stf(bf16* p, float v)  { *p = __float2bfloat16(v); }

__device__ __forceinline__ void gload_lds16(const bf16* g, bf16* l) {
    __builtin_amdgcn_global_load_lds(
        (const __attribute__((address_space(1))) void*)g,
        (__attribute__((address_space(3))) void*)l, 16, 0, 0);
}

// ---------------------------------------------------------------------------
__global__ void k_rpe_pos(const float* __restrict__ w, const float* __restrict__ bias,
                          float* __restrict__ out) {
    int p = blockIdx.x;
    float ii = (float)(p / 27 - 13);
    float jj = (float)(p % 27 - 13);
    for (int c = threadIdx.x; c < 512; c += 256)
        out[p * 512 + c] = ii * w[c] + jj * w[512 + c] + bias[c];
}

// ---------------------------------------------------------------------------
// out[r][:] = relu(in[r][:] * rsqrt(mean(in[r]^2)+eps)); out bf16 for MFMA A.
template <typename TO>
__global__ void k_rmsnorm_relu(const float* __restrict__ in, TO* __restrict__ out) {
    int r = blockIdx.x;
    const float* x = in + (size_t)r * 512;
    float v0 = x[threadIdx.x];
    float v1 = x[threadIdx.x + 256];
    float s = v0 * v0 + v1 * v1;
    #pragma unroll
    for (int off = 32; off; off >>= 1) s += __shfl_down(s, off, 64);
    __shared__ float ps[4];
    if ((threadIdx.x & 63) == 0) ps[threadIdx.x >> 6] = s;
    __syncthreads();
    float tot = ps[0] + ps[1] + ps[2] + ps[3];
    float scale = rsqrtf(tot * (1.0f / 512.0f) + RMS_EPS);
    stf(&out[(size_t)r * 512 + threadIdx.x],       fmaxf(v0 * scale, 0.0f));
    stf(&out[(size_t)r * 512 + threadIdx.x + 256], fmaxf(v1 * scale, 0.0f));
}

// ---------------------------------------------------------------------------
// Small-tile MFMA GEMM for the RPE chain: 64x64 tile, BK=32, 4 waves.
// A bf16 [M][K] (rows beyond M read garbage, discarded at store), Bt bf16 [N][K].
// EPI: 0 = bias only (fp32 out), 2 = bias + Toeplitz decay (bf16 out).
template <int EPI, typename TO>
__global__ __launch_bounds__(256) void k_mgemm_s(const bf16* __restrict__ A,
                                                 const bf16* __restrict__ Bt,
                                                 const float* __restrict__ bias,
                                                 TO* __restrict__ out,
                                                 int M, int N, int K) {
    __shared__ bf16 As[64 * 32];
    __shared__ bf16 Bs[64 * 32];
    const int tid = threadIdx.x;
    const int m0 = blockIdx.y * 64;
    const int n0 = blockIdx.x * 64;
    const int lane = tid & 63;
    const int w = tid >> 6;           // wave = m-frag index
    const int lr = lane & 15;
    const int lk = (lane >> 4) * 8;

    f32x4 acc[4] = {};

    const int row = tid >> 2;         // 0..63
    const int seg = (tid & 3) * 8;

    for (int k0 = 0; k0 < K; k0 += 32) {
        gload_lds16(&A[(size_t)(m0 + row) * K + k0 + seg], &As[tid * 8]);
        gload_lds16(&Bt[(size_t)(n0 + row) * K + k0 + seg], &Bs[tid * 8]);
        __syncthreads();
        bf16x8 af = *(const bf16x8*)&As[(w * 16 + lr) * 32 + lk];
        #pragma unroll
        for (int j = 0; j < 4; ++j) {
            bf16x8 bf = *(const bf16x8*)&Bs[(j * 16 + lr) * 32 + lk];
            acc[j] = __builtin_amdgcn_mfma_f32_16x16x32_bf16(af, bf, acc[j], 0, 0, 0);
        }
        __syncthreads();
    }

    const int crow = (lane >> 4) * 4;
    const int ccol = lane & 15;
    #pragma unroll
    for (int j = 0; j < 4; ++j) {
        int gc = n0 + j * 16 + ccol;
        float bb = bias[gc];
        #pragma unroll
        for (int r = 0; r < 4; ++r) {
            int gr = m0 + w * 16 + crow + r;
            if (gr < M) {
                float val = acc[j][r] + bb;
                if (EPI == 2) {
                    int i = gr / 27, jj = gr % 27;
                    val *= exp2f((float)(abs(i - 13) + abs(jj - 13)) * GAMMA_LOG2);
                }
                stf(&out[(size_t)gr * N + gc], val);
            }
        }
    }
}

// ---------------------------------------------------------------------------
// MFMA bf16 GEMM (m97 structure): 128x128 tile, BK=32, 4 waves, 4x4 frags.
template <int EPI, typename TO>
__global__ __launch_bounds__(256) void k_mgemm(const bf16* __restrict__ A, int lda,
                                               const bf16* __restrict__ Bt,
                                               const float* __restrict__ bias,
                                               TO* __restrict__ out, int ldo,
                                               int M, int N, int K) {
    __shared__ bf16 As[128 * 32];
    __shared__ bf16 Bs[128 * 32];
    const int tid = threadIdx.x;
    const int m0 = blockIdx.y * 128;
    const int n0 = blockIdx.x * 128;
    const int lane = tid & 63;
    const int w = tid >> 6;
    const int wr = (w >> 1) * 64;
    const int wc = (w & 1) * 64;
    const int lr = lane & 15;
    const int lk = (lane >> 4) * 8;

    f32x4 acc[4][4] = {};

    for (int k0 = 0; k0 < K; k0 += 32) {
        #pragma unroll
        for (int t = 0; t < 2; ++t) {
            int flat = t * 256 + tid;
            int row = flat >> 2;
            int seg = (flat & 3) * 8;
            gload_lds16(&A[(size_t)(m0 + row) * lda + k0 + seg], &As[flat * 8]);
            gload_lds16(&Bt[(size_t)(n0 + row) * K + k0 + seg], &Bs[flat * 8]);
        }
        __syncthreads();
        bf16x8 af[4], bf[4];
        #pragma unroll
        for (int i = 0; i < 4; ++i) {
            af[i] = *(const bf16x8*)&As[(wr + i * 16 + lr) * 32 + lk];
            bf[i] = *(const bf16x8*)&Bs[(wc + i * 16 + lr) * 32 + lk];
        }
        #pragma unroll
        for (int i = 0; i < 4; ++i)
            #pragma unroll
            for (int j = 0; j < 4; ++j)
                acc[i][j] = __builtin_amdgcn_mfma_f32_16x16x32_bf16(af[i], bf[j], acc[i][j], 0, 0, 0);
        __syncthreads();
    }

    const int crow = (lane >> 4) * 4;
    const int ccol = lane & 15;
    #pragma unroll
    for (int i = 0; i < 4; ++i)
        #pragma unroll
        for (int j = 0; j < 4; ++j) {
            int gc = n0 + wc + j * 16 + ccol;
            float bb = bias[gc];
            #pragma unroll
            for (int r = 0; r < 4; ++r) {
                int gr = m0 + wr + i * 16 + crow + r;
                float val = acc[i][j][r] + bb;
                if (EPI == 1) val = val / (1.0f + expf(-val));
                stf(&out[(size_t)gr * ldo + gc], val);
            }
        }
}

// ---------------------------------------------------------------------------
// fp32 [R][C] -> bf16 [C][R] transpose (weights prep)
__global__ __launch_bounds__(256) void k_transpose(const float* __restrict__ src,
                                                   bf16* __restrict__ dst, int R, int C) {
    __shared__ float t[32][33];
    int bx = blockIdx.x * 32;
    int by = blockIdx.y * 32;
    int tx = threadIdx.x & 31, ty = threadIdx.x >> 5;
    #pragma unroll
    for (int i = 0; i < 4; ++i)
        t[ty + i * 8][tx] = src[(size_t)(by + ty + i * 8) * C + bx + tx];
    __syncthreads();
    #pragma unroll
    for (int i = 0; i < 4; ++i)
        dst[(size_t)(bx + ty + i * 8) * R + by + tx] = __float2bfloat16(t[tx][ty + i * 8]);
}

// ---------------------------------------------------------------------------
__global__ void k_cvt_bf16(const float* __restrict__ src, bf16* __restrict__ dst, int n4) {
    int i = blockIdx.x * blockDim.x + threadIdx.x;
    if (i < n4) {
        float4 v = *(const float4*)&src[i * 4];
        bf16* d = &dst[i * 4];
        d[0] = __float2bfloat16(v.x);
        d[1] = __float2bfloat16(v.y);
        d[2] = __float2bfloat16(v.z);
        d[3] = __float2bfloat16(v.w);
    }
}

__global__ void k_bias_uv(const float* __restrict__ bu, const float* __restrict__ bv,
                          float* __restrict__ dst) {
    int c = blockIdx.x * 256 + threadIdx.x;
    if (c < 2048) dst[c] = (c < 1024) ? bu[c] : bv[c - 1024];
}

// ---------------------------------------------------------------------------
// v channel transpose: Vt[c][b][ij(pad 224)] = v[b*196+ij][c]
__global__ __launch_bounds__(256) void k_vt(const bf16* __restrict__ uv,
                                            bf16* __restrict__ Vt) {
    const int c0 = blockIdx.x * 64;
    const int b  = blockIdx.y;
    const int tid = threadIdx.x;
    __shared__ bf16 t[196][66];
    for (int f = tid; f < 196 * 64; f += 256) {
        int ij = f >> 6, cl = f & 63;
        t[ij][cl] = uv[((size_t)b * 196 + ij) * 2048 + 1024 + c0 + cl];
    }
    __syncthreads();
    const bf16 z = __float2bfloat16(0.0f);
    for (int f = tid; f < 64 * 224; f += 256) {
        int cl = f / 224, ij = f - cl * 224;
        Vt[((size_t)(c0 + cl) * 64 + b) * 224 + ij] = (ij < 196) ? t[ij][cl] : z;
    }
}

// ---------------------------------------------------------------------------
// Per-channel Toeplitz GEMM v2: Yt[cl][pq][b] = sum_ij T_c[pq][ij] * Vt[c][b][ij]
// Block = (m-half, channel). Wave w owns n-tile w (b = w*16..), hoisting its 7
// B-fragments into registers (each read ONCE per block from L2-resident Vt).
// T-slice built in LDS with hoisted per-thread (i,j) and incremental (p,q).
__global__ __launch_bounds__(256) void k_convm(const bf16* __restrict__ Ab,
                                               const bf16* __restrict__ Vt,
                                               bf16* __restrict__ Yt, int cbase) {
    __shared__ __align__(16) bf16 Ts[112 * 232];
    __shared__ bf16 As[736];
    const int mh = blockIdx.x;               // 0 / 1
    const int cl = blockIdx.y;               // 0..511
    const int c = cbase + cl;
    const int tid = threadIdx.x;
    const int mbase = mh * 112;

    for (int e = tid; e < 729; e += 256)
        As[e] = Ab[(size_t)e * 1024 + c];
    __syncthreads();

    // --- build T-slice: rows r=0..111 (pq = mbase+r), cols t=0..223 (ij) ---
    const bf16 z = __float2bfloat16(0.0f);
    if (tid < 224) {
        const int i = tid / 14, j = tid - i * 14;
        const bool kvalid = tid < 196;
        int p = mbase / 14, q = 0;           // mbase is 0 or 112 (=8*14)
        for (int r = 0; r < 112; ++r) {
            bf16 val = z;
            if (kvalid && (mbase + r) < 196)
                val = As[(p - i + 13) * 27 + (q - j + 13)];
            Ts[r * 232 + tid] = val;
            if (++q == 14) { q = 0; ++p; }
        }
    }
    __syncthreads();

    const int lane = tid & 63;
    const int w = tid >> 6;                  // n-tile (b group) this wave owns
    const int lr = lane & 15;
    const int lk = (lane >> 4) * 8;
    const bf16* Vc = Vt + (size_t)c * 64 * 224;

    bf16x8 bfr[7];
    #pragma unroll
    for (int ks = 0; ks < 7; ++ks)
        bfr[ks] = *(const bf16x8*)&Vc[(size_t)(w * 16 + lr) * 224 + ks * 32 + lk];

    f32x4 acc[7] = {};
    #pragma unroll
    for (int ks = 0; ks < 7; ++ks)
        #pragma unroll
        for (int mi = 0; mi < 7; ++mi) {
            bf16x8 a = *(const bf16x8*)&Ts[(mi * 16 + lr) * 232 + ks * 32 + lk];
            acc[mi] = __builtin_amdgcn_mfma_f32_16x16x32_bf16(a, bfr[ks], acc[mi], 0, 0, 0);
        }

    const int crow = (lane >> 4) * 4;
    const int bb = w * 16 + (lane & 15);
    #pragma unroll
    for (int mi = 0; mi < 7; ++mi) {
        int pq = mbase + mi * 16 + crow;
        #pragma unroll
        for (int r = 0; r < 4; ++r)
            if (pq + r < 196)
                Yt[((size_t)cl * 196 + pq + r) * 64 + bb] = __float2bfloat16(acc[mi][r]);
    }
}

// ---------------------------------------------------------------------------
// Gate + transpose back: uv.v[b*196+pq][c] = u[b*196+pq][c] * Yt[c-cbase][pq][b]
__global__ __launch_bounds__(256) void k_gate(bf16* __restrict__ uv,
                                              const bf16* __restrict__ Yt, int cbase) {
    const int pq = blockIdx.x;       // 0..195
    const int ct = blockIdx.y;       // 0..7
    const int tid = threadIdx.x;
    __shared__ float t[64][65];
    for (int f = tid; f < 64 * 64; f += 256) {
        int cr = f >> 6, bcol = f & 63;
        t[cr][bcol] = __bfloat162float(Yt[((size_t)(ct * 64 + cr) * 196 + pq) * 64 + bcol]);
    }
    __syncthreads();
    for (int f = tid; f < 64 * 64; f += 256) {
        int br = f >> 6, cc = f & 63;
        size_t row = (size_t)br * 196 + pq;
        int cglob = cbase + ct * 64 + cc;
        float uu = __bfloat162float(uv[row * 2048 + cglob]);
        uv[row * 2048 + 1024 + cglob] = __float2bfloat16(t[cc][br] * uu);
    }
}

// ---------------------------------------------------------------------------
extern "C" void kernel_launch(void* const* d_in, const int* in_sizes, int n_in,
                              void* d_out, int out_size, void* d_ws, size_t ws_size,
                              hipStream_t stream) {
    const float* x    = (const float*)d_in[0];
    const float* Wu   = (const float*)d_in[3];
    const float* bu   = (const float*)d_in[4];
    const float* Wv   = (const float*)d_in[5];
    const float* bv   = (const float*)d_in[6];
    const float* Wo   = (const float*)d_in[7];
    const float* bo   = (const float*)d_in[8];
    const float* rpw  = (const float*)d_in[9];
    const float* rpb  = (const float*)d_in[10];
    const float* w1   = (const float*)d_in[11];
    const float* b1   = (const float*)d_in[12];
    const float* w2   = (const float*)d_in[13];
    const float* b2   = (const float*)d_in[14];
    const float* w3   = (const float*)d_in[15];
    const float* b3   = (const float*)d_in[16];
    const float* wOut = (const float*)d_in[17];
    const float* bOut = (const float*)d_in[18];

    char* ws = (char*)d_ws;
    size_t off = 0;
    auto take = [&](size_t bytes) { char* p = ws + off; off += (bytes + 255) & ~size_t(255); return p; };
    float* rA     = (float*)take((size_t)RPOS * 512 * 4);
    float* rB     = (float*)take((size_t)RPOS * 512 * 4);
    bf16*  rn     = (bf16*)take((size_t)RPOS * 512 * 2 + 40960);  // +tail slack for OOB-safe reads
    bf16*  Ab     = (bf16*)take((size_t)RPOS * 1024 * 2);
    bf16*  xb     = (bf16*)take((size_t)ROWS * EE * 2);           // reused as Yt
    bf16*  WuvT   = (bf16*)take((size_t)2048 * 512 * 2);
    bf16*  WoT    = (bf16*)take((size_t)512 * 1024 * 2);
    bf16*  w1T    = (bf16*)take((size_t)512 * 512 * 2);
    bf16*  w2T    = (bf16*)take((size_t)512 * 512 * 2);
    bf16*  w3T    = (bf16*)take((size_t)512 * 512 * 2);
    bf16*  wOutT  = (bf16*)take((size_t)1024 * 512 * 2);
    float* biasUv = (float*)take(2048 * 4);
    bf16*  uvb    = (bf16*)take((size_t)ROWS * 2048 * 2);
    bf16*  Vt     = (bf16*)take((size_t)1024 * 64 * 224 * 2);
    bf16*  Yt     = (bf16*)xb;

    // --- weight prep (bf16, transposed to [N][K]) ---
    k_transpose<<<dim3(32, 16), 256, 0, stream>>>(Wu, WuvT, 512, 1024);
    k_transpose<<<dim3(32, 16), 256, 0, stream>>>(Wv, WuvT + (size_t)1024 * 512, 512, 1024);
    k_transpose<<<dim3(16, 32), 256, 0, stream>>>(Wo, WoT, 1024, 512);
    k_transpose<<<dim3(16, 16), 256, 0, stream>>>(w1, w1T, 512, 512);
    k_transpose<<<dim3(16, 16), 256, 0, stream>>>(w2, w2T, 512, 512);
    k_transpose<<<dim3(16, 16), 256, 0, stream>>>(w3, w3T, 512, 512);
    k_transpose<<<dim3(32, 16), 256, 0, stream>>>(wOut, wOutT, 512, 1024);
    k_bias_uv<<<8, 256, 0, stream>>>(bu, bv, biasUv);
    k_cvt_bf16<<<(ROWS * EE / 4 + 255) / 256, 256, 0, stream>>>(x, xb, ROWS * EE / 4);

    // --- RPE MLP (MFMA small tiles) ---
    k_rpe_pos<<<RPOS, 256, 0, stream>>>(rpw, rpb, rA);
    k_rmsnorm_relu<bf16><<<RPOS, 256, 0, stream>>>(rA, rn);
    k_mgemm_s<0, float><<<dim3(8, 12), 256, 0, stream>>>(rn, w1T, b1, rB, RPOS, 512, 512);
    k_rmsnorm_relu<bf16><<<RPOS, 256, 0, stream>>>(rB, rn);
    k_mgemm_s<0, float><<<dim3(8, 12), 256, 0, stream>>>(rn, w2T, b2, rA, RPOS, 512, 512);
    k_rmsnorm_relu<bf16><<<RPOS, 256, 0, stream>>>(rA, rn);
    k_mgemm_s<0, float><<<dim3(8, 12), 256, 0, stream>>>(rn, w3T, b3, rB, RPOS, 512, 512);
    k_rmsnorm_relu<bf16><<<RPOS, 256, 0, stream>>>(rB, rn);
    k_mgemm_s<2, bf16><<<dim3(16, 12), 256, 0, stream>>>(rn, wOutT, bOut, Ab, RPOS, 1024, 512);

    // --- uv = silu(x @ [Wu|Wv] + [bu|bv]) ---
    k_mgemm<1, bf16><<<dim3(16, 98), 256, 0, stream>>>(xb, 512, WuvT, biasUv, uvb, 2048,
                                                       ROWS, 2048, 512);

    // --- v -> channel-major Vt (padded to 224) ---
    k_vt<<<dim3(16, 64), 256, 0, stream>>>(uvb, Vt);

    // --- Toeplitz conv (MFMA) + gating, two 512-channel halves ---
    for (int h = 0; h < 2; ++h) {
        k_convm<<<dim3(2, 512), 256, 0, stream>>>(Ab, Vt, Yt, h * 512);
        k_gate<<<dim3(196, 8), 256, 0, stream>>>(uvb, Yt, h * 512);
    }

    // --- out = g @ Wo + bo ---
    k_mgemm<0, float><<<dim3(4, 98), 256, 0, stream>>>(uvb + 1024, 2048, WoT, bo,
                                                       (float*)d_out, 512, ROWS, 512, 1024);
}